// Round 16
// baseline (146.976 us; speedup 1.0000x reference)
//
#include <hip/hip_runtime.h>
#include <cmath>

#define TSEQ 256
#define TMEL 1024
#define DDIM 80
#define NBATCH 64

#define K2E 1.44269504089f
#define LN2f 0.693147181f
#define EPS2 (1e-4f * K2E)
#define NEGB (-10000.0f * K2E)
// cubic fit of log2(1+e), e in [0,1]; max abs err ~1.1e-3; PC0E folds +EPS2 per step
#define PC3 0.1543704f
#define PC2 (-0.5699672f)
#define PC1 1.4152454f
#define PC0E (0.0010908f + EPS2)

#define TH 16
#define HALO 5
#define TR (TH + 2 * HALO)   // 26
#define SVW 97               // row stride % 32 == 1 -> conflict-free window reads

#define LDS_T_STRIDE 260     // [t][s] f32 rows: %32==4 spreads banks, *4B 16B-aligned
#define CHUNK_FLOATS (16 * LDS_T_STRIDE)   // 4160 (chunk = 16 t-steps)
#define NSLOT 4

#define NB_TRANS (NBATCH * 64)           // 4096 transpose tiles (64t x 64s)
#define NB_SSIM (NBATCH * (TMEL / TH))   // 4096
#define NB_DUR 8

typedef float f4 __attribute__((ext_vector_type(4)));
typedef float f2 __attribute__((ext_vector_type(2)));
typedef int   i2 __attribute__((ext_vector_type(2)));

__device__ __forceinline__ unsigned lds_addr(const float* p) {
    return (unsigned)(unsigned long long)(__attribute__((address_space(3))) const float*)p;
}

// log2-domain logaddexp step; raw v_exp_f32 (R13: -45 cyc/step vs OCML exp2f)
__device__ __forceinline__ float lstep(float x, float y, float lp) {
    float d = x - y;
    float m = fmaxf(x, y);
    float e = __builtin_amdgcn_exp2f(-fabsf(d));
    float t = fmaf(e, PC3, PC2);
    t = fmaf(e, t, PC1);
    t = fmaf(e, t, PC0E);
    return fmaf(lp, K2E, m) + t;
}

// ---------------- MDN scan: R15 6-wave structure, bf16 lpT producer ----------------
// R15 finding: per-CU fetch wall ~6 B/cyc (depth-invariant). R16: halve bytes.
// lpT[b][t][s] bf16 (pre-transposed). Producer wave loads one 512-B contiguous
// row per instr (dwordx2/lane), converts bf16->f32 (2 shifts) into LDS f32.
// Consumer waves 4,5 byte-identical to R15 (passed).
__global__ __launch_bounds__(384, 1)
void mdn_scan(const unsigned short* __restrict__ lpT, const float* __restrict__ logp,
              const int* __restrict__ mel_lens, const int* __restrict__ text_lens,
              float* __restrict__ alpha_out)
{
    __shared__ __align__(16) float ldsf[NSLOT * CHUNK_FLOATS + 32];
    const int tid = threadIdx.x;
    const int wv = tid >> 6, lane = tid & 63;
    const int b = blockIdx.x;
    const int tmax = mel_lens[b] - 1;    // 511..1023 (uniform per block)
    const int sf   = text_lens[b] - 1;   // 127..255
    const int klast = tmax >> 4;         // 31..63
    float* ring = ldsf + NSLOT * CHUNK_FLOATS;   // 2 x 16 floats

    // consumer state (waves 4,5)
    float a0 = NEGB, a1 = NEGB, cap0 = NEGB, cap1 = NEGB, carry = NEGB;
    const int negbi = __float_as_int(NEGB);
    const bool rs = ((lane & 15) == 0), isl0 = (lane == 0);

    // producer state: ONE 16-row register set per wave (i2 = 8B = 4 bf16 = s 4l..4l+3)
    i2 G0, G1, G2, G3, G4, G5, G6, G7, G8, G9, G10, G11, G12, G13, G14, G15;
    const unsigned short* pg = lpT + ((size_t)b << 18) + (lane << 2);

#define MBAR { asm volatile("s_waitcnt lgkmcnt(0)" ::: "memory"); \
               __builtin_amdgcn_s_barrier(); }

#define PISSB(c) { \
    const unsigned short* _p = pg + ((size_t)(c) << 12); \
    asm volatile("global_load_dwordx2 %0, %1, off" : "=v"(G0)  : "v"(_p)); \
    asm volatile("global_load_dwordx2 %0, %1, off" : "=v"(G1)  : "v"(_p + (1 << 8))); \
    asm volatile("global_load_dwordx2 %0, %1, off" : "=v"(G2)  : "v"(_p + (2 << 8))); \
    asm volatile("global_load_dwordx2 %0, %1, off" : "=v"(G3)  : "v"(_p + (3 << 8))); \
    asm volatile("global_load_dwordx2 %0, %1, off" : "=v"(G4)  : "v"(_p + (4 << 8))); \
    asm volatile("global_load_dwordx2 %0, %1, off" : "=v"(G5)  : "v"(_p + (5 << 8))); \
    asm volatile("global_load_dwordx2 %0, %1, off" : "=v"(G6)  : "v"(_p + (6 << 8))); \
    asm volatile("global_load_dwordx2 %0, %1, off" : "=v"(G7)  : "v"(_p + (7 << 8))); \
    asm volatile("global_load_dwordx2 %0, %1, off" : "=v"(G8)  : "v"(_p + (8 << 8))); \
    asm volatile("global_load_dwordx2 %0, %1, off" : "=v"(G9)  : "v"(_p + (9 << 8))); \
    asm volatile("global_load_dwordx2 %0, %1, off" : "=v"(G10) : "v"(_p + (10 << 8))); \
    asm volatile("global_load_dwordx2 %0, %1, off" : "=v"(G11) : "v"(_p + (11 << 8))); \
    asm volatile("global_load_dwordx2 %0, %1, off" : "=v"(G12) : "v"(_p + (12 << 8))); \
    asm volatile("global_load_dwordx2 %0, %1, off" : "=v"(G13) : "v"(_p + (13 << 8))); \
    asm volatile("global_load_dwordx2 %0, %1, off" : "=v"(G14) : "v"(_p + (14 << 8))); \
    asm volatile("global_load_dwordx2 %0, %1, off" : "=v"(G15) : "v"(_p + (15 << 8))); \
}
#define VW0 asm volatile("s_waitcnt vmcnt(0)" ::: "memory")
// convert 4 bf16 -> 4 f32, one ds_write_b128 per row (lane covers s=4l..4l+3)
#define CVW(R, k, D) { const int _r0 = R[0], _r1 = R[1]; f4 _w; \
    _w[0] = __int_as_float(_r0 << 16); \
    _w[1] = __int_as_float(_r0 & 0xffff0000); \
    _w[2] = __int_as_float(_r1 << 16); \
    _w[3] = __int_as_float(_r1 & 0xffff0000); \
    *(f4*)((D) + (k) * LDS_T_STRIDE) = _w; }
#define PWRTB(sp) { float* _d = (sp) + (lane << 2); \
    CVW(G0,0,_d)  CVW(G1,1,_d)  CVW(G2,2,_d)  CVW(G3,3,_d) \
    CVW(G4,4,_d)  CVW(G5,5,_d)  CVW(G6,6,_d)  CVW(G7,7,_d) \
    CVW(G8,8,_d)  CVW(G9,9,_d)  CVW(G10,10,_d) CVW(G11,11,_d) \
    CVW(G12,12,_d) CVW(G13,13,_d) CVW(G14,14,_d) CVW(G15,15,_d) }

#define DSR64(dst, off) asm volatile("ds_read_b64 %0, %1 offset:" #off : "=v"(dst) : "v"(a3));
#define DSR128(dst, off) asm volatile("ds_read_b128 %0, %1 offset:" #off : "=v"(dst) : "v"(a3r));
#define LDSFENCE asm volatile("s_waitcnt lgkmcnt(0)" ::: "memory"); __builtin_amdgcn_sched_barrier(0);

#define LDALL16 \
    f2 _v0,_v1,_v2,_v3,_v4,_v5,_v6,_v7,_v8,_v9,_v10,_v11,_v12,_v13,_v14,_v15; \
    DSR64(_v0, 0)      DSR64(_v1, 1040)   DSR64(_v2, 2080)   DSR64(_v3, 3120) \
    DSR64(_v4, 4160)   DSR64(_v5, 5200)   DSR64(_v6, 6240)   DSR64(_v7, 7280) \
    DSR64(_v8, 8320)   DSR64(_v9, 9360)   DSR64(_v10, 10400) DSR64(_v11, 11440) \
    DSR64(_v12, 12480) DSR64(_v13, 13520) DSR64(_v14, 14560) DSR64(_v15, 15600)

#define CS0(j) { \
    const int xi = __float_as_int(a1); \
    const int s1 = __builtin_amdgcn_update_dpp(negbi, xi, 0x111, 0xF, 0xF, false); \
    const int s2 = __builtin_amdgcn_update_dpp(s1, xi, 0x142, 0xE, 0xF, false); \
    const float prev = __int_as_float(rs ? s2 : s1); \
    const float o0 = a0; \
    a0 = lstep(a0, prev, _v##j[0]); \
    a1 = lstep(a1, o0, _v##j[1]); \
    r##j = a1; \
    if (t0 + (j) == tmax) { cap0 = a0; cap1 = a1; } \
}
#define CS1(j, RV) { \
    const int xi = __float_as_int(a1); \
    const int s1 = __builtin_amdgcn_update_dpp(negbi, xi, 0x111, 0xF, 0xF, false); \
    const int s2 = __builtin_amdgcn_update_dpp(s1, xi, 0x142, 0xE, 0xF, false); \
    float prev = __int_as_float(rs ? s2 : s1); \
    prev = isl0 ? (RV) : prev; \
    const float o0 = a0; \
    a0 = lstep(a0, prev, _v##j[0]); \
    a1 = lstep(a1, o0, _v##j[1]); \
    if (tb + (j) == tmax) { cap0 = a0; cap1 = a1; } \
}

#define CONS0_BODY(I) { \
    const float* bufp = ldsf + ((I) & 3) * CHUNK_FLOATS + (lane << 1); \
    const unsigned a3 = lds_addr(bufp); \
    LDALL16 \
    LDSFENCE \
    const int t0 = (I) << 4; \
    float r0,r1,r2,r3,r4,r5,r6,r7,r8,r9,r10,r11,r12,r13,r14,r15; \
    if ((I) == 0) { \
        r0 = a1; \
        CS0(1) CS0(2) CS0(3) CS0(4) CS0(5) CS0(6) CS0(7) CS0(8) \
        CS0(9) CS0(10) CS0(11) CS0(12) CS0(13) CS0(14) CS0(15) \
    } else { \
        CS0(0) CS0(1) CS0(2) CS0(3) CS0(4) CS0(5) CS0(6) CS0(7) \
        CS0(8) CS0(9) CS0(10) CS0(11) CS0(12) CS0(13) CS0(14) CS0(15) \
    } \
    if (lane == 63) { \
        float* rg = ring + (((I) & 1) << 4); \
        *(float4*)(rg)      = make_float4(r0, r1, r2, r3); \
        *(float4*)(rg + 4)  = make_float4(r4, r5, r6, r7); \
        *(float4*)(rg + 8)  = make_float4(r8, r9, r10, r11); \
        *(float4*)(rg + 12) = make_float4(r12, r13, r14, r15); \
    } \
}
#define CONS1_BODY(I) { \
    const int cc = (I) - 1; \
    const float* bufp = ldsf + (cc & 3) * CHUNK_FLOATS + 128 + (lane << 1); \
    const unsigned a3 = lds_addr(bufp); \
    const unsigned a3r = lds_addr(ring + ((cc & 1) << 4)); \
    LDALL16 \
    f4 q0, q1, q2, q3; \
    DSR128(q0, 0) DSR128(q1, 16) DSR128(q2, 32) DSR128(q3, 48) \
    LDSFENCE \
    const int tb = cc << 4; \
    if (cc == 0) { \
        CS1(1,q0[0]) CS1(2,q0[1]) CS1(3,q0[2]) CS1(4,q0[3]) CS1(5,q1[0]) \
        CS1(6,q1[1]) CS1(7,q1[2]) CS1(8,q1[3]) CS1(9,q2[0]) CS1(10,q2[1]) \
        CS1(11,q2[2]) CS1(12,q2[3]) CS1(13,q3[0]) CS1(14,q3[1]) CS1(15,q3[2]) \
    } else { \
        CS1(0,carry) CS1(1,q0[0]) CS1(2,q0[1]) CS1(3,q0[2]) CS1(4,q0[3]) \
        CS1(5,q1[0]) CS1(6,q1[1]) CS1(7,q1[2]) CS1(8,q1[3]) CS1(9,q2[0]) \
        CS1(10,q2[1]) CS1(11,q2[2]) CS1(12,q2[3]) CS1(13,q3[0]) CS1(14,q3[1]) CS1(15,q3[2]) \
    } \
    carry = q3[3]; \
}

    // prologue: waves 0-3 issue chunks 0-3; wave 0 retires+writes chunk 0
    if (wv < 4) {
        PISSB(wv)
        if (wv == 0) { VW0; PWRTB(ldsf) }             // chunk 0 -> slot 0
    } else if (wv == 4) {
        __builtin_amdgcn_s_setprio(1);
        a0 = (lane == 0) ? logp[(size_t)b << 18] * K2E : NEGB;  // alpha0[0] (exact f32)
    } else {
        __builtin_amdgcn_s_setprio(1);
    }
    MBAR

    const int Jmax = klast + 1;
    for (int J = 0; J <= Jmax; ++J) {
        if (wv < 4) {
            if (wv == (J & 3) && J + 4 <= klast) {
                PISSB(J + 4)                           // issue 3 sub-iters ahead
            }
            if (wv == ((J + 1) & 3) && J + 1 <= klast) {
                VW0;                                   // own loads only (per-wave vmcnt)
                float* sp = ldsf + ((J + 1) & 3) * CHUNK_FLOATS;
                PWRTB(sp)                              // chunk J+1 -> slot (J+1)%4
            }
        } else if (wv == 4) {
            if (J <= klast) CONS0_BODY(J)
        } else {
            if (J >= 1) CONS1_BODY(J)
        }
        MBAR
    }

    if (wv == 4 && sf < 128) {
        float va = (sf & 1) ? cap1 : cap0;
        float res = __shfl(va, sf >> 1);
        if (lane == 0) alpha_out[b] = res * LN2f;
    } else if (wv == 5 && sf >= 128) {
        const int sl = sf - 128;
        float va = (sl & 1) ? cap1 : cap0;
        float res = __shfl(va, sl >> 1);
        if (lane == 0) alpha_out[b] = res * LN2f;
    }
#undef MBAR
#undef PISSB
#undef VW0
#undef CVW
#undef PWRTB
#undef DSR64
#undef DSR128
#undef LDSFENCE
#undef LDALL16
#undef CS0
#undef CS1
#undef CONS0_BODY
#undef CONS1_BODY
}

// ---------------- transpose+convert: logp[b][s][t] f32 -> lpT[b][t][s] bf16 ----------------
__device__ __forceinline__ void trans_body(float (*tile)[65], int blk,
        const float* __restrict__ logp, unsigned short* __restrict__ lpT)
{
    const int tid = threadIdx.x;
    const int b = blk >> 6, rem = blk & 63;
    const int tt = rem >> 2, st = rem & 3;          // 16 t-tiles x 4 s-tiles
    const int sbase = st << 6, tbase = tt << 6;
    const float* src = logp + ((size_t)b << 18) + ((size_t)sbase << 10) + tbase;

#pragma unroll
    for (int i = 0; i < 4; ++i) {
        int idx = tid + (i << 8);
        int sl = idx >> 4, t4 = (idx & 15) << 2;    // 64 s-rows x 64 t
        float4 v = *(const float4*)(src + ((size_t)sl << 10) + t4);
        tile[sl][t4 + 0] = v.x; tile[sl][t4 + 1] = v.y;
        tile[sl][t4 + 2] = v.z; tile[sl][t4 + 3] = v.w;
    }
    __syncthreads();
#pragma unroll
    for (int i = 0; i < 2; ++i) {
        int idx = tid + (i << 8);
        int trow = idx >> 3, sg = idx & 7;          // 64 t-rows x 8 s-groups of 8
        unsigned u0, u1, u2, u3, u4, u5, u6, u7;
#define BF16RNE(dst, ff) { unsigned _x = __float_as_uint(ff); \
        dst = (_x + 0x7fffu + ((_x >> 16) & 1u)) >> 16; }
        BF16RNE(u0, tile[(sg << 3) + 0][trow]) BF16RNE(u1, tile[(sg << 3) + 1][trow])
        BF16RNE(u2, tile[(sg << 3) + 2][trow]) BF16RNE(u3, tile[(sg << 3) + 3][trow])
        BF16RNE(u4, tile[(sg << 3) + 4][trow]) BF16RNE(u5, tile[(sg << 3) + 5][trow])
        BF16RNE(u6, tile[(sg << 3) + 6][trow]) BF16RNE(u7, tile[(sg << 3) + 7][trow])
#undef BF16RNE
        uint4 o;
        o.x = u0 | (u1 << 16); o.y = u2 | (u3 << 16);
        o.z = u4 | (u5 << 16); o.w = u6 | (u7 << 16);
        *(uint4*)(lpT + ((size_t)b << 18) + ((size_t)(tbase + trow) << 8)
                  + sbase + (sg << 3)) = o;
    }
}

// ---------------- SSIM + fused masked spec-MSE + dur partials ----------------
struct SsimSmem {
    float sx[TR][DDIM];
    float sy[TR][DDIM];
    float sv[5][TH][SVW];
    float wred[8];
};

__device__ __forceinline__ float4 fma4(float w, const float4 a, float4 acc) {
    acc.x = fmaf(w, a.x, acc.x); acc.y = fmaf(w, a.y, acc.y);
    acc.z = fmaf(w, a.z, acc.z); acc.w = fmaf(w, a.w, acc.w); return acc;
}
__device__ __forceinline__ float4 mul4(const float4 a, const float4 b) {
    return make_float4(a.x * b.x, a.y * b.y, a.z * b.z, a.w * b.w);
}

__device__ __forceinline__ void ssim_body(SsimSmem* sm, int blk,
        const float* __restrict__ xg, const float* __restrict__ yg,
        const int* __restrict__ lens,
        float* __restrict__ ssim_part, float* __restrict__ spec_part)
{
    const int tid = threadIdx.x;
    const int b  = blk >> 6;
    const int r0 = (blk & 63) * TH;
    const int len = lens[b];
    const float* px = xg + (size_t)b * (TMEL * DDIM);
    const float* py = yg + (size_t)b * (TMEL * DDIM);

    float g[11];
    {
        float s = 0.f;
#pragma unroll
        for (int i = 0; i < 11; ++i) {
            float t = (float)((i - 5) * (i - 5));
            g[i] = expf(-t / 4.5f);
            s += g[i];
        }
        float inv = 1.0f / s;
#pragma unroll
        for (int i = 0; i < 11; ++i) g[i] *= inv;
    }

    for (int i = tid; i < 5 * TH * 10; i += 256) {
        int f = i / (TH * 10);
        int rem = i - f * (TH * 10);
        int r = rem / 10;
        int c = rem - r * 10;
        int cc = (c < 5) ? (3 + c) : (83 + c);
        sm->sv[f][r][cc] = 0.f;
    }

    float aspec = 0.f;
    for (int i = tid; i < TR * 20; i += 256) {
        int rr = i / 20, c4 = (i % 20) << 2;
        int gr = r0 - HALO + rr;
        float4 vx = make_float4(0.f, 0.f, 0.f, 0.f);
        float4 vy = make_float4(0.f, 0.f, 0.f, 0.f);
        if (gr >= 0 && gr < len) {
            vx = *(const float4*)(px + (size_t)gr * DDIM + c4);
            vy = *(const float4*)(py + (size_t)gr * DDIM + c4);
        }
        *(float4*)&sm->sx[rr][c4] = vx;
        *(float4*)&sm->sy[rr][c4] = vy;
        if (rr >= HALO && rr < HALO + TH) {
            float dx = vx.x - vy.x, dy = vx.y - vy.y, dz = vx.z - vy.z, dw = vx.w - vy.w;
            aspec += dx * dx + dy * dy + dz * dz + dw * dw;
        }
    }
    __syncthreads();

    for (int i = tid; i < TH * 20; i += 256) {
        int rr = i / 20, c4 = (i % 20) << 2;
        float4 m1 = make_float4(0,0,0,0), m2 = m1, xx = m1, yy = m1, xy = m1;
#pragma unroll
        for (int kk = 0; kk < 11; ++kk) {
            float w = g[kk];
            const float4 x = *(const float4*)&sm->sx[rr + kk][c4];
            const float4 y = *(const float4*)&sm->sy[rr + kk][c4];
            m1 = fma4(w, x, m1);
            m2 = fma4(w, y, m2);
            xx = fma4(w, mul4(x, x), xx);
            yy = fma4(w, mul4(y, y), yy);
            xy = fma4(w, mul4(x, y), xy);
        }
        *(float4*)&sm->sv[0][rr][8 + c4] = m1;
        *(float4*)&sm->sv[1][rr][8 + c4] = m2;
        *(float4*)&sm->sv[2][rr][8 + c4] = xx;
        *(float4*)&sm->sv[3][rr][8 + c4] = yy;
        *(float4*)&sm->sv[4][rr][8 + c4] = xy;
    }
    __syncthreads();

    float assim = 0.f;
    for (int i = tid; i < TH * 20; i += 256) {
        int rr = i / 20, c4 = (i % 20) << 2;
        float4 am[5];
        float wa[5], wb[5], wc[5], wd[5];
#pragma unroll
        for (int f = 0; f < 5; ++f) {
            am[f] = make_float4(0,0,0,0);
            wa[f] = sm->sv[f][rr][c4 + 3];
            wb[f] = sm->sv[f][rr][c4 + 4];
            wc[f] = sm->sv[f][rr][c4 + 5];
            wd[f] = sm->sv[f][rr][c4 + 6];
        }
#pragma unroll
        for (int kk = 0; kk < 11; ++kk) {
            float w = g[kk];
#pragma unroll
            for (int f = 0; f < 5; ++f) {
                am[f].x = fmaf(w, wa[f], am[f].x);
                am[f].y = fmaf(w, wb[f], am[f].y);
                am[f].z = fmaf(w, wc[f], am[f].z);
                am[f].w = fmaf(w, wd[f], am[f].w);
                wa[f] = wb[f]; wb[f] = wc[f]; wc[f] = wd[f];
                if (kk < 10) wd[f] = sm->sv[f][rr][c4 + 7 + kk];
            }
        }
#define SSIMC(C) { \
        float mu1 = am[0].C, mu2 = am[1].C, vxx = am[2].C, vyy = am[3].C, vxy = am[4].C; \
        float mu1s = mu1 * mu1, mu2s = mu2 * mu2, mu12 = mu1 * mu2; \
        float num = (2.f * mu12 + 1e-4f) * (2.f * (vxy - mu12) + 9e-4f); \
        float den = (mu1s + mu2s + 1e-4f) * ((vxx - mu1s) + (vyy - mu2s) + 9e-4f); \
        assim += num / den; }
        SSIMC(x) SSIMC(y) SSIMC(z) SSIMC(w)
#undef SSIMC
    }

#pragma unroll
    for (int o = 32; o > 0; o >>= 1) {
        assim += __shfl_down(assim, o);
        aspec += __shfl_down(aspec, o);
    }
    if ((tid & 63) == 0) { sm->wred[tid >> 6] = assim; sm->wred[4 + (tid >> 6)] = aspec; }
    __syncthreads();
    if (tid == 0) {
        ssim_part[blk] = sm->wred[0] + sm->wred[1] + sm->wred[2] + sm->wred[3];
        spec_part[blk] = sm->wred[4] + sm->wred[5] + sm->wred[6] + sm->wred[7];
    }
}

__device__ __forceinline__ void dur_body(float* sred, int blk2,
        const float* __restrict__ duro, const float* __restrict__ durt,
        const int* __restrict__ ilens, float* __restrict__ dur_part)
{
    const int tid = threadIdx.x;
    float s = 0.f;
    int i = blk2 * 2048 + tid;
#pragma unroll
    for (int it = 0; it < 8; ++it, i += 256) {
        int bb = i >> 8, ss = i & 255;
        float d = duro[i] - durt[i];
        s += (ss < ilens[bb]) ? d * d : 0.f;
    }
#pragma unroll
    for (int o = 32; o > 0; o >>= 1) s += __shfl_down(s, o);
    if ((tid & 63) == 0) sred[tid >> 6] = s;
    __syncthreads();
    if (tid == 0) dur_part[blk2] = sred[0] + sred[1] + sred[2] + sred[3];
}

// ---------------- fused prep kernel: transpose + ssim + dur ----------------
__global__ __launch_bounds__(256, 3)
void prep_fused(const float* __restrict__ logp, unsigned short* __restrict__ lpT,
                const float* __restrict__ deco, const float* __restrict__ dect,
                const int* __restrict__ dlens,
                const float* __restrict__ duro, const float* __restrict__ durt,
                const int* __restrict__ ilens,
                float* __restrict__ ssim_p, float* __restrict__ spec_p,
                float* __restrict__ dur_p)
{
    __shared__ __align__(16) char smem[sizeof(SsimSmem)];
    const int bx = blockIdx.x;
    if (bx < NB_TRANS) {
        trans_body((float(*)[65])smem, bx, logp, lpT);
    } else if (bx < NB_TRANS + NB_SSIM) {
        ssim_body((SsimSmem*)smem, bx - NB_TRANS, deco, dect, dlens, ssim_p, spec_p);
    } else {
        dur_body(((SsimSmem*)smem)->wred, bx - NB_TRANS - NB_SSIM, duro, durt, ilens, dur_p);
    }
}

// ---------------- final combine ----------------
__device__ __forceinline__ float block_sum(float v, float* sred, int tid) {
#pragma unroll
    for (int o = 32; o > 0; o >>= 1) v += __shfl_down(v, o);
    __syncthreads();
    if ((tid & 63) == 0) sred[tid >> 6] = v;
    __syncthreads();
    return sred[0] + sred[1] + sred[2] + sred[3];
}

__global__ __launch_bounds__(256)
void final_kernel(const float* __restrict__ ssim_p, const float* __restrict__ spec_p,
                  const float* __restrict__ dur_p, const float* __restrict__ alpha,
                  const int* __restrict__ dlens, const int* __restrict__ ilens,
                  float* __restrict__ out)
{
    __shared__ float sred[4];
    const int tid = threadIdx.x;
    float s_ssim = 0, s_spec = 0, s_alpha = 0, s_dur = 0, c_spec = 0, c_dur = 0;
    for (int i = tid; i < NB_SSIM; i += 256) { s_ssim += ssim_p[i]; s_spec += spec_p[i]; }
    if (tid < NB_DUR) s_dur = dur_p[tid];
    for (int i = tid; i < NBATCH; i += 256) {
        s_alpha += alpha[i];
        int dl = dlens[i]; if (dl > TMEL) dl = TMEL;
        int il = ilens[i]; if (il > TSEQ) il = TSEQ;
        c_spec += (float)dl;
        c_dur  += (float)il;
    }
    float S_ssim  = block_sum(s_ssim, sred, tid);
    float S_spec  = block_sum(s_spec, sred, tid);
    float S_alpha = block_sum(s_alpha, sred, tid);
    float S_dur   = block_sum(s_dur, sred, tid);
    float C_spec  = block_sum(c_spec, sred, tid);
    float C_dur   = block_sum(c_dur, sred, tid);

    if (tid == 0) {
        float spec_loss = S_spec / (C_spec * (float)DDIM);
        float ssim_loss = 1.0f - S_ssim / (float)(NBATCH * TMEL * DDIM);
        float dur_loss  = S_dur / C_dur;
        float mdn_loss  = -(S_alpha / (float)NBATCH) / (float)TSEQ;
        out[0] = spec_loss + ssim_loss + dur_loss + mdn_loss;
        out[1] = spec_loss;
        out[2] = ssim_loss;
        out[3] = dur_loss;
        out[4] = mdn_loss;
    }
}

extern "C" void kernel_launch(void* const* d_in, const int* in_sizes, int n_in,
                              void* d_out, int out_size, void* d_ws, size_t ws_size,
                              hipStream_t stream) {
    const float* logp  = (const float*)d_in[0];
    const float* deco  = (const float*)d_in[1];
    const float* dect  = (const float*)d_in[2];
    const int*   dlens = (const int*)d_in[3];
    const float* duro  = (const float*)d_in[4];
    const float* durt  = (const float*)d_in[5];
    const int*   ilens = (const int*)d_in[6];

    float* ws     = (float*)d_ws;
    float* ssim_p = ws;                                   // 4096
    float* spec_p = ssim_p + NB_SSIM;                     // 4096
    float* dur_p  = spec_p + NB_SSIM;                     // 8
    float* alpha  = dur_p + NB_DUR;                       // 64
    unsigned short* lpT = (unsigned short*)(ws + 16384);  // 64*1024*256 bf16 = 32 MB

    prep_fused<<<NB_TRANS + NB_SSIM + NB_DUR, 256, 0, stream>>>(
        logp, lpT, deco, dect, dlens, duro, durt, ilens, ssim_p, spec_p, dur_p);
    mdn_scan<<<NBATCH, 384, 0, stream>>>(lpT, logp, dlens, ilens, alpha);
    final_kernel<<<1, 256, 0, stream>>>(ssim_p, spec_p, dur_p, alpha,
                                        dlens, ilens, (float*)d_out);
}

// Round 17
// 80.741 us; speedup vs baseline: 1.8204x; 1.8204x over previous
//
#include <hip/hip_runtime.h>
#include <cmath>

#define TSEQ 256
#define TMEL 1024
#define DDIM 80
#define NBATCH 64

#define K2E 1.44269504089f
#define LN2f 0.693147181f
#define EPS2 (1e-4f * K2E)
#define NEGB (-10000.0f * K2E)
// cubic fit of log2(1+e), e in [0,1]; max abs err ~1.1e-3; PC0E folds +EPS2 per step
#define PC3 0.1543704f
#define PC2 (-0.5699672f)
#define PC1 1.4152454f
#define PC0E (0.0010908f + EPS2)

#define TH 16
#define HALO 5
#define TR (TH + 2 * HALO)   // 26
#define SVW 97               // row stride % 32 == 1 -> conflict-free window reads

#define LDS_T_STRIDE 260     // [t][s] rows: %32==4 spreads banks, *4B is 16B-aligned
#define CHUNK_FLOATS (16 * LDS_T_STRIDE)   // 4160 (chunk = 16 t-steps)

#define NB_MDN 64
#define NB_SSIM (NBATCH * (TMEL / TH))   // 4096
#define NB_DUR 8

typedef float f4 __attribute__((ext_vector_type(4)));
typedef float f2 __attribute__((ext_vector_type(2)));

struct SsimSmem {
    float sx[TR][DDIM];
    float sy[TR][DDIM];
    float sv[5][TH][SVW];
    float wred[8];
};
#define MDN_SMEM_BYTES ((3 * CHUNK_FLOATS + 32) * 4)
#define SMEM_BYTES ((sizeof(SsimSmem) > (size_t)MDN_SMEM_BYTES) ? sizeof(SsimSmem) : (size_t)MDN_SMEM_BYTES)

__device__ __forceinline__ unsigned lds_addr(const float* p) {
    return (unsigned)(unsigned long long)(__attribute__((address_space(3))) const float*)p;
}

// log2-domain logaddexp step; raw v_exp_f32 (R13-validated: -45 cyc/step vs OCML)
__device__ __forceinline__ float lstep(float x, float y, float lp) {
    float d = x - y;
    float m = fmaxf(x, y);
    float e = __builtin_amdgcn_exp2f(-fabsf(d));
    float t = fmaf(e, PC3, PC2);
    t = fmaf(e, t, PC1);
    t = fmaf(e, t, PC0E);
    return fmaf(lp, K2E, m) + t;
}

// ---------------- MDN forward scan: 4-wave pipeline (R12 structure + exp2 fix) ----------------
__device__ __forceinline__ void mdn_body(float* ldsf,
        const float* __restrict__ logp, const int* __restrict__ mel_lens,
        const int* __restrict__ text_lens, float* __restrict__ alpha_out)
{
    const int tid = threadIdx.x;
    const int wv = tid >> 6, lane = tid & 63;
    const int b = blockIdx.x;
    const int tmax = mel_lens[b] - 1;    // 511..1023 (uniform per block)
    const int sf   = text_lens[b] - 1;   // 127..255
    const int klast = tmax >> 4;         // 31..63
    const int Niter = (klast + 3) & ~1;  // even, >= klast+2
    float* ring = ldsf + 3 * CHUNK_FLOATS;   // 2 x 16 floats

    // consumer state (live only in waves 2,3)
    float a0 = NEGB, a1 = NEGB, cap0 = NEGB, cap1 = NEGB, carry = NEGB;
    const int negbi = __float_as_int(NEGB);
    const bool rs = ((lane & 15) == 0), isl0 = (lane == 0);

    // producer state
    f4 A0, A1, A2, A3, A4, A5, A6, A7, B0, B1, B2, B3, B4, B5, B6, B7;
    const float* pgbase = logp + ((size_t)b << 18)
                        + ((size_t)((wv << 7) + (lane >> 2)) << 10) + ((lane & 3) << 2);
    const int woff = (lane & 3) * 4 * LDS_T_STRIDE + (wv << 7) + (lane >> 2);

// counted barrier: LDS drained (writes visible), global loads stay in flight
#define MBAR { asm volatile("s_waitcnt lgkmcnt(0)" ::: "memory"); \
               __builtin_amdgcn_s_barrier(); }

#define PISS(R0,R1,R2,R3,R4,R5,R6,R7, c) { \
    const float* _p = pgbase + ((size_t)(c) << 4); \
    asm volatile("global_load_dwordx4 %0, %1, off" : "=v"(R0) : "v"(_p)); \
    asm volatile("global_load_dwordx4 %0, %1, off" : "=v"(R1) : "v"(_p + (1 << 14))); \
    asm volatile("global_load_dwordx4 %0, %1, off" : "=v"(R2) : "v"(_p + (2 << 14))); \
    asm volatile("global_load_dwordx4 %0, %1, off" : "=v"(R3) : "v"(_p + (3 << 14))); \
    asm volatile("global_load_dwordx4 %0, %1, off" : "=v"(R4) : "v"(_p + (4 << 14))); \
    asm volatile("global_load_dwordx4 %0, %1, off" : "=v"(R5) : "v"(_p + (5 << 14))); \
    asm volatile("global_load_dwordx4 %0, %1, off" : "=v"(R6) : "v"(_p + (6 << 14))); \
    asm volatile("global_load_dwordx4 %0, %1, off" : "=v"(R7) : "v"(_p + (7 << 14))); \
}
#define PFENCE asm volatile("s_waitcnt vmcnt(8)" ::: "memory")
#define PWR1(R, k, D) { (D)[(k)*16] = R[0]; (D)[(k)*16 + LDS_T_STRIDE] = R[1]; \
                        (D)[(k)*16 + 2*LDS_T_STRIDE] = R[2]; (D)[(k)*16 + 3*LDS_T_STRIDE] = R[3]; }
#define PWRT(R0,R1,R2,R3,R4,R5,R6,R7, sp) { float* _d = (sp) + woff; \
    PWR1(R0,0,_d) PWR1(R1,1,_d) PWR1(R2,2,_d) PWR1(R3,3,_d) \
    PWR1(R4,4,_d) PWR1(R5,5,_d) PWR1(R6,6,_d) PWR1(R7,7,_d) }

    // asm LDS reads: literal byte offsets j*1040 off one address register
#define DSR64(dst, off) asm volatile("ds_read_b64 %0, %1 offset:" #off : "=v"(dst) : "v"(a3));
#define DSR128(dst, off) asm volatile("ds_read_b128 %0, %1 offset:" #off : "=v"(dst) : "v"(a3r));
#define LDSFENCE asm volatile("s_waitcnt lgkmcnt(0)" ::: "memory"); __builtin_amdgcn_sched_barrier(0);

#define LDALL16 \
    f2 _v0,_v1,_v2,_v3,_v4,_v5,_v6,_v7,_v8,_v9,_v10,_v11,_v12,_v13,_v14,_v15; \
    DSR64(_v0, 0)      DSR64(_v1, 1040)   DSR64(_v2, 2080)   DSR64(_v3, 3120) \
    DSR64(_v4, 4160)   DSR64(_v5, 5200)   DSR64(_v6, 6240)   DSR64(_v7, 7280) \
    DSR64(_v8, 8320)   DSR64(_v9, 9360)   DSR64(_v10, 10400) DSR64(_v11, 11440) \
    DSR64(_v12, 12480) DSR64(_v13, 13520) DSR64(_v14, 14560) DSR64(_v15, 15600)

#define CS0(j) { \
    const int xi = __float_as_int(a1); \
    const int s1 = __builtin_amdgcn_update_dpp(negbi, xi, 0x111, 0xF, 0xF, false); \
    const int s2 = __builtin_amdgcn_update_dpp(s1, xi, 0x142, 0xE, 0xF, false); \
    const float prev = __int_as_float(rs ? s2 : s1); \
    const float o0 = a0; \
    a0 = lstep(a0, prev, _v##j[0]); \
    a1 = lstep(a1, o0, _v##j[1]); \
    r##j = a1; \
    if (t0 + (j) == tmax) { cap0 = a0; cap1 = a1; } \
}
#define CS1(j, RV) { \
    const int xi = __float_as_int(a1); \
    const int s1 = __builtin_amdgcn_update_dpp(negbi, xi, 0x111, 0xF, 0xF, false); \
    const int s2 = __builtin_amdgcn_update_dpp(s1, xi, 0x142, 0xE, 0xF, false); \
    float prev = __int_as_float(rs ? s2 : s1); \
    prev = isl0 ? (RV) : prev; \
    const float o0 = a0; \
    a0 = lstep(a0, prev, _v##j[0]); \
    a1 = lstep(a1, o0, _v##j[1]); \
    if (tb + (j) == tmax) { cap0 = a0; cap1 = a1; } \
}

#define CONS0_BODY(I) { \
    const float* bufp = ldsf + ((I) % 3) * CHUNK_FLOATS + (lane << 1); \
    const unsigned a3 = lds_addr(bufp); \
    LDALL16 \
    LDSFENCE \
    const int t0 = (I) << 4; \
    float r0,r1,r2,r3,r4,r5,r6,r7,r8,r9,r10,r11,r12,r13,r14,r15; \
    if ((I) == 0) { \
        r0 = a1; \
        CS0(1) CS0(2) CS0(3) CS0(4) CS0(5) CS0(6) CS0(7) CS0(8) \
        CS0(9) CS0(10) CS0(11) CS0(12) CS0(13) CS0(14) CS0(15) \
    } else { \
        CS0(0) CS0(1) CS0(2) CS0(3) CS0(4) CS0(5) CS0(6) CS0(7) \
        CS0(8) CS0(9) CS0(10) CS0(11) CS0(12) CS0(13) CS0(14) CS0(15) \
    } \
    if (lane == 63) { \
        float* rg = ring + (((I) & 1) << 4); \
        *(float4*)(rg)      = make_float4(r0, r1, r2, r3); \
        *(float4*)(rg + 4)  = make_float4(r4, r5, r6, r7); \
        *(float4*)(rg + 8)  = make_float4(r8, r9, r10, r11); \
        *(float4*)(rg + 12) = make_float4(r12, r13, r14, r15); \
    } \
}
#define CONS1_BODY(I) { \
    const int cc = (I) - 1; \
    const float* bufp = ldsf + (cc % 3) * CHUNK_FLOATS + 128 + (lane << 1); \
    const unsigned a3 = lds_addr(bufp); \
    const unsigned a3r = lds_addr(ring + ((cc & 1) << 4)); \
    LDALL16 \
    f4 q0, q1, q2, q3; \
    DSR128(q0, 0) DSR128(q1, 16) DSR128(q2, 32) DSR128(q3, 48) \
    LDSFENCE \
    const int tb = cc << 4; \
    if (cc == 0) { \
        CS1(1,q0[0]) CS1(2,q0[1]) CS1(3,q0[2]) CS1(4,q0[3]) CS1(5,q1[0]) \
        CS1(6,q1[1]) CS1(7,q1[2]) CS1(8,q1[3]) CS1(9,q2[0]) CS1(10,q2[1]) \
        CS1(11,q2[2]) CS1(12,q2[3]) CS1(13,q3[0]) CS1(14,q3[1]) CS1(15,q3[2]) \
    } else { \
        CS1(0,carry) CS1(1,q0[0]) CS1(2,q0[1]) CS1(3,q0[2]) CS1(4,q0[3]) \
        CS1(5,q1[0]) CS1(6,q1[1]) CS1(7,q1[2]) CS1(8,q1[3]) CS1(9,q2[0]) \
        CS1(10,q2[1]) CS1(11,q2[2]) CS1(12,q2[3]) CS1(13,q3[0]) CS1(14,q3[1]) CS1(15,q3[2]) \
    } \
    carry = q3[3]; \
}

    // prologue
    if (wv < 2) {
        PISS(A0,A1,A2,A3,A4,A5,A6,A7, 0)
        asm volatile("s_waitcnt vmcnt(0)" ::: "memory");
        PWRT(A0,A1,A2,A3,A4,A5,A6,A7, ldsf)           // chunk 0 -> slot 0
        PISS(B0,B1,B2,B3,B4,B5,B6,B7, 1)
    } else {
        __builtin_amdgcn_s_setprio(1);
        if (wv == 2) a0 = (lane == 0) ? logp[(size_t)b << 18] * K2E : NEGB;  // alpha0
    }
    MBAR

    for (int i = 0; i < Niter; i += 2) {
        // even iter i: issue->A, write B (chunk i+1) -> slot (i+1)%3
        if (wv < 2) {
            const int c2 = (i + 2 < klast) ? (i + 2) : klast;
            PISS(A0,A1,A2,A3,A4,A5,A6,A7, c2)
            PFENCE;
            float* sp = ldsf + ((i + 1) % 3) * CHUNK_FLOATS;
            PWRT(B0,B1,B2,B3,B4,B5,B6,B7, sp)
        } else if (wv == 2) {
            if (i <= klast) CONS0_BODY(i)
        } else {
            if (i >= 1 && i <= klast + 1) CONS1_BODY(i)
        }
        MBAR
        // odd iter i+1: issue->B, write A (chunk i+2) -> slot (i+2)%3
        if (wv < 2) {
            const int c2 = (i + 3 < klast) ? (i + 3) : klast;
            PISS(B0,B1,B2,B3,B4,B5,B6,B7, c2)
            PFENCE;
            float* sp = ldsf + ((i + 2) % 3) * CHUNK_FLOATS;
            PWRT(A0,A1,A2,A3,A4,A5,A6,A7, sp)
        } else if (wv == 2) {
            if (i + 1 <= klast) CONS0_BODY(i + 1)
        } else {
            if (i + 1 >= 1 && i + 1 <= klast + 1) CONS1_BODY(i + 1)
        }
        MBAR
    }

    if (wv == 2 && sf < 128) {
        float va = (sf & 1) ? cap1 : cap0;
        float res = __shfl(va, sf >> 1);
        if (lane == 0) alpha_out[b] = res * LN2f;
    } else if (wv == 3 && sf >= 128) {
        const int sl = sf - 128;
        float va = (sl & 1) ? cap1 : cap0;
        float res = __shfl(va, sl >> 1);
        if (lane == 0) alpha_out[b] = res * LN2f;
    }
#undef MBAR
#undef PISS
#undef PFENCE
#undef PWR1
#undef PWRT
#undef DSR64
#undef DSR128
#undef LDSFENCE
#undef LDALL16
#undef CS0
#undef CS1
#undef CONS0_BODY
#undef CONS1_BODY
}

// ---------------- SSIM + fused masked spec-MSE ----------------
__device__ __forceinline__ float4 fma4(float w, const float4 a, float4 acc) {
    acc.x = fmaf(w, a.x, acc.x); acc.y = fmaf(w, a.y, acc.y);
    acc.z = fmaf(w, a.z, acc.z); acc.w = fmaf(w, a.w, acc.w); return acc;
}
__device__ __forceinline__ float4 mul4(const float4 a, const float4 b) {
    return make_float4(a.x * b.x, a.y * b.y, a.z * b.z, a.w * b.w);
}

__device__ __forceinline__ void ssim_body(SsimSmem* sm, int blk,
        const float* __restrict__ xg, const float* __restrict__ yg,
        const int* __restrict__ lens,
        float* __restrict__ ssim_part, float* __restrict__ spec_part)
{
    const int tid = threadIdx.x;
    const int b  = blk >> 6;
    const int r0 = (blk & 63) * TH;
    const int len = lens[b];
    const float* px = xg + (size_t)b * (TMEL * DDIM);
    const float* py = yg + (size_t)b * (TMEL * DDIM);

    float g[11];
    {
        float s = 0.f;
#pragma unroll
        for (int i = 0; i < 11; ++i) {
            float t = (float)((i - 5) * (i - 5));
            g[i] = expf(-t / 4.5f);
            s += g[i];
        }
        float inv = 1.0f / s;
#pragma unroll
        for (int i = 0; i < 11; ++i) g[i] *= inv;
    }

    for (int i = tid; i < 5 * TH * 10; i += 256) {
        int f = i / (TH * 10);
        int rem = i - f * (TH * 10);
        int r = rem / 10;
        int c = rem - r * 10;
        int cc = (c < 5) ? (3 + c) : (83 + c);
        sm->sv[f][r][cc] = 0.f;
    }

    float aspec = 0.f;
    for (int i = tid; i < TR * 20; i += 256) {
        int rr = i / 20, c4 = (i % 20) << 2;
        int gr = r0 - HALO + rr;
        float4 vx = make_float4(0.f, 0.f, 0.f, 0.f);
        float4 vy = make_float4(0.f, 0.f, 0.f, 0.f);
        if (gr >= 0 && gr < len) {
            vx = *(const float4*)(px + (size_t)gr * DDIM + c4);
            vy = *(const float4*)(py + (size_t)gr * DDIM + c4);
        }
        *(float4*)&sm->sx[rr][c4] = vx;
        *(float4*)&sm->sy[rr][c4] = vy;
        if (rr >= HALO && rr < HALO + TH) {
            float dx = vx.x - vy.x, dy = vx.y - vy.y, dz = vx.z - vy.z, dw = vx.w - vy.w;
            aspec += dx * dx + dy * dy + dz * dz + dw * dw;
        }
    }
    __syncthreads();

    for (int i = tid; i < TH * 20; i += 256) {
        int rr = i / 20, c4 = (i % 20) << 2;
        float4 m1 = make_float4(0,0,0,0), m2 = m1, xx = m1, yy = m1, xy = m1;
#pragma unroll
        for (int kk = 0; kk < 11; ++kk) {
            float w = g[kk];
            const float4 x = *(const float4*)&sm->sx[rr + kk][c4];
            const float4 y = *(const float4*)&sm->sy[rr + kk][c4];
            m1 = fma4(w, x, m1);
            m2 = fma4(w, y, m2);
            xx = fma4(w, mul4(x, x), xx);
            yy = fma4(w, mul4(y, y), yy);
            xy = fma4(w, mul4(x, y), xy);
        }
        *(float4*)&sm->sv[0][rr][8 + c4] = m1;
        *(float4*)&sm->sv[1][rr][8 + c4] = m2;
        *(float4*)&sm->sv[2][rr][8 + c4] = xx;
        *(float4*)&sm->sv[3][rr][8 + c4] = yy;
        *(float4*)&sm->sv[4][rr][8 + c4] = xy;
    }
    __syncthreads();

    float assim = 0.f;
    for (int i = tid; i < TH * 20; i += 256) {
        int rr = i / 20, c4 = (i % 20) << 2;
        float4 am[5];
        float wa[5], wb[5], wc[5], wd[5];
#pragma unroll
        for (int f = 0; f < 5; ++f) {
            am[f] = make_float4(0,0,0,0);
            wa[f] = sm->sv[f][rr][c4 + 3];
            wb[f] = sm->sv[f][rr][c4 + 4];
            wc[f] = sm->sv[f][rr][c4 + 5];
            wd[f] = sm->sv[f][rr][c4 + 6];
        }
#pragma unroll
        for (int kk = 0; kk < 11; ++kk) {
            float w = g[kk];
#pragma unroll
            for (int f = 0; f < 5; ++f) {
                am[f].x = fmaf(w, wa[f], am[f].x);
                am[f].y = fmaf(w, wb[f], am[f].y);
                am[f].z = fmaf(w, wc[f], am[f].z);
                am[f].w = fmaf(w, wd[f], am[f].w);
                wa[f] = wb[f]; wb[f] = wc[f]; wc[f] = wd[f];
                if (kk < 10) wd[f] = sm->sv[f][rr][c4 + 7 + kk];
            }
        }
#define SSIMC(C) { \
        float mu1 = am[0].C, mu2 = am[1].C, vxx = am[2].C, vyy = am[3].C, vxy = am[4].C; \
        float mu1s = mu1 * mu1, mu2s = mu2 * mu2, mu12 = mu1 * mu2; \
        float num = (2.f * mu12 + 1e-4f) * (2.f * (vxy - mu12) + 9e-4f); \
        float den = (mu1s + mu2s + 1e-4f) * ((vxx - mu1s) + (vyy - mu2s) + 9e-4f); \
        assim += num / den; }
        SSIMC(x) SSIMC(y) SSIMC(z) SSIMC(w)
#undef SSIMC
    }

#pragma unroll
    for (int o = 32; o > 0; o >>= 1) {
        assim += __shfl_down(assim, o);
        aspec += __shfl_down(aspec, o);
    }
    if ((tid & 63) == 0) { sm->wred[tid >> 6] = assim; sm->wred[4 + (tid >> 6)] = aspec; }
    __syncthreads();
    if (tid == 0) {
        ssim_part[blk] = sm->wred[0] + sm->wred[1] + sm->wred[2] + sm->wred[3];
        spec_part[blk] = sm->wred[4] + sm->wred[5] + sm->wred[6] + sm->wred[7];
    }
}

// ---------------- dur-loss partial sums ----------------
__device__ __forceinline__ void dur_body(float* sred, int blk2,
        const float* __restrict__ duro, const float* __restrict__ durt,
        const int* __restrict__ ilens, float* __restrict__ dur_part)
{
    const int tid = threadIdx.x;
    float s = 0.f;
    int i = blk2 * 2048 + tid;
#pragma unroll
    for (int it = 0; it < 8; ++it, i += 256) {
        int bb = i >> 8, ss = i & 255;
        float d = duro[i] - durt[i];
        s += (ss < ilens[bb]) ? d * d : 0.f;
    }
#pragma unroll
    for (int o = 32; o > 0; o >>= 1) s += __shfl_down(s, o);
    if ((tid & 63) == 0) sred[tid >> 6] = s;
    __syncthreads();
    if (tid == 0) dur_part[blk2] = sred[0] + sred[1] + sred[2] + sred[3];
}

// ---------------- fused main kernel ----------------
__global__ __launch_bounds__(256, 3)
void fused_main(const float* __restrict__ logp,
                const int* __restrict__ dlens, const int* __restrict__ ilens,
                const float* __restrict__ deco, const float* __restrict__ dect,
                const float* __restrict__ duro, const float* __restrict__ durt,
                float* __restrict__ alpha, float* __restrict__ ssim_p,
                float* __restrict__ spec_p, float* __restrict__ dur_p)
{
    __shared__ __align__(16) char smem[SMEM_BYTES];
    const int bx = blockIdx.x;
    if (bx < NB_MDN) {
        mdn_body((float*)smem, logp, dlens, ilens, alpha);
    } else if (bx < NB_MDN + NB_SSIM) {
        ssim_body((SsimSmem*)smem, bx - NB_MDN, deco, dect, dlens, ssim_p, spec_p);
    } else {
        dur_body((float*)smem, bx - NB_MDN - NB_SSIM, duro, durt, ilens, dur_p);
    }
}

// ---------------- final combine ----------------
__device__ __forceinline__ float block_sum(float v, float* sred, int tid) {
#pragma unroll
    for (int o = 32; o > 0; o >>= 1) v += __shfl_down(v, o);
    __syncthreads();
    if ((tid & 63) == 0) sred[tid >> 6] = v;
    __syncthreads();
    return sred[0] + sred[1] + sred[2] + sred[3];
}

__global__ __launch_bounds__(256)
void final_kernel(const float* __restrict__ ssim_p, const float* __restrict__ spec_p,
                  const float* __restrict__ dur_p, const float* __restrict__ alpha,
                  const int* __restrict__ dlens, const int* __restrict__ ilens,
                  float* __restrict__ out)
{
    __shared__ float sred[4];
    const int tid = threadIdx.x;
    float s_ssim = 0, s_spec = 0, s_alpha = 0, s_dur = 0, c_spec = 0, c_dur = 0;
    for (int i = tid; i < NB_SSIM; i += 256) { s_ssim += ssim_p[i]; s_spec += spec_p[i]; }
    if (tid < NB_DUR) s_dur = dur_p[tid];
    for (int i = tid; i < NBATCH; i += 256) {
        s_alpha += alpha[i];
        int dl = dlens[i]; if (dl > TMEL) dl = TMEL;
        int il = ilens[i]; if (il > TSEQ) il = TSEQ;
        c_spec += (float)dl;
        c_dur  += (float)il;
    }
    float S_ssim  = block_sum(s_ssim, sred, tid);
    float S_spec  = block_sum(s_spec, sred, tid);
    float S_alpha = block_sum(s_alpha, sred, tid);
    float S_dur   = block_sum(s_dur, sred, tid);
    float C_spec  = block_sum(c_spec, sred, tid);
    float C_dur   = block_sum(c_dur, sred, tid);

    if (tid == 0) {
        float spec_loss = S_spec / (C_spec * (float)DDIM);
        float ssim_loss = 1.0f - S_ssim / (float)(NBATCH * TMEL * DDIM);
        float dur_loss  = S_dur / C_dur;
        float mdn_loss  = -(S_alpha / (float)NBATCH) / (float)TSEQ;
        out[0] = spec_loss + ssim_loss + dur_loss + mdn_loss;
        out[1] = spec_loss;
        out[2] = ssim_loss;
        out[3] = dur_loss;
        out[4] = mdn_loss;
    }
}

extern "C" void kernel_launch(void* const* d_in, const int* in_sizes, int n_in,
                              void* d_out, int out_size, void* d_ws, size_t ws_size,
                              hipStream_t stream) {
    const float* logp  = (const float*)d_in[0];
    const float* deco  = (const float*)d_in[1];
    const float* dect  = (const float*)d_in[2];
    const int*   dlens = (const int*)d_in[3];
    const float* duro  = (const float*)d_in[4];
    const float* durt  = (const float*)d_in[5];
    const int*   ilens = (const int*)d_in[6];

    float* ws     = (float*)d_ws;
    float* ssim_p = ws;                       // 4096
    float* spec_p = ssim_p + NB_SSIM;         // 4096
    float* dur_p  = spec_p + NB_SSIM;         // 8
    float* alpha  = dur_p + NB_DUR;           // 64

    fused_main<<<NB_MDN + NB_SSIM + NB_DUR, 256, 0, stream>>>(
        logp, dlens, ilens, deco, dect, duro, durt, alpha, ssim_p, spec_p, dur_p);
    final_kernel<<<1, 256, 0, stream>>>(ssim_p, spec_p, dur_p, alpha,
                                        dlens, ilens, (float*)d_out);
}